// Round 8
// baseline (76.062 us; speedup 1.0000x reference)
//
#include <hip/hip_runtime.h>
#include <math.h>

#define DIM 3072
#define SEQ 8192
#define NROWS (3 * DIM)   // 9216 GEMV output rows

__device__ __forceinline__ float silu_f(float v) {
    return v / (1.0f + __expf(-v));
}

// One W row per wave (4 rows per 256-thread block). silu(emb) staged in LDS
// once per block (single barrier); wave-local shuffle reduction only.
// (round-3 proven version, unchanged)
__global__ __launch_bounds__(256, 4) void gemv3_kernel(
    const float* __restrict__ emb, const float* __restrict__ W,
    const float* __restrict__ b, float* __restrict__ shift,
    float* __restrict__ scale, float* __restrict__ gate)
{
    __shared__ float s[DIM];
    const int t = threadIdx.x;
    const float4* emb4 = (const float4*)emb;
    float4* s4 = (float4*)s;

    #pragma unroll
    for (int k = 0; k < 3; ++k) {
        int i = t + k * 256;                 // float4 index < 768
        float4 v = emb4[i];
        v.x = silu_f(v.x); v.y = silu_f(v.y);
        v.z = silu_f(v.z); v.w = silu_f(v.w);
        s4[i] = v;
    }
    __syncthreads();

    const int wid = t >> 6;
    const int lane = t & 63;
    const int row = blockIdx.x * 4 + wid;    // 0..NROWS-1, grid = NROWS/4
    const float4* w4 = (const float4*)(W + (size_t)row * DIM);

    float acc = 0.f;
    #pragma unroll
    for (int k = 0; k < 12; ++k) {
        float4 w = w4[lane + 64 * k];
        float4 v = s4[lane + 64 * k];
        acc += w.x * v.x + w.y * v.y + w.z * v.z + w.w * v.w;
    }

    #pragma unroll
    for (int off = 32; off > 0; off >>= 1)
        acc += __shfl_xor(acc, off, 64);

    if (lane == 0) {
        float e = acc + b[row];
        int i = row / 3;
        int r = row - 3 * i;
        if (r == 0)      shift[i] = e;
        else if (r == 1) scale[i] = e;
        else             gate[i]  = e;
    }
}

// Pass 1: per-row mean/rstd. Wave-per-row, pure read stream (no data kept,
// no stores except 8 B/row). Lean VGPR -> full occupancy.
__global__ __launch_bounds__(256, 4) void ln_stats_kernel(
    const float* __restrict__ x, float2* __restrict__ stats)
{
    const int t = threadIdx.x;
    const int wid = t >> 6;
    const int lane = t & 63;
    const int row = blockIdx.x * 4 + wid;    // grid = SEQ/4 = 2048
    const float4* x4 = (const float4*)(x + (size_t)row * DIM);

    float sum = 0.f, sq = 0.f;
    #pragma unroll
    for (int k = 0; k < 12; ++k) {
        float4 v = x4[lane + 64 * k];
        sum += v.x + v.y + v.z + v.w;
        sq  += v.x * v.x + v.y * v.y + v.z * v.z + v.w * v.w;
    }

    #pragma unroll
    for (int off = 32; off > 0; off >>= 1) {
        sum += __shfl_xor(sum, off, 64);
        sq  += __shfl_xor(sq,  off, 64);
    }

    if (lane == 0) {
        float mean = sum * (1.0f / DIM);
        float rstd = rsqrtf(sq * (1.0f / DIM) - mean * mean + 1e-6f);
        stats[row] = make_float2(mean, rstd);
    }
}

// Pass 2: apply. Block-per-row, pure elementwise copy-pattern: no reduce,
// no barrier, no cross-lane. x re-read is MALL-resident (brought in by pass 1;
// x 100.7MB + W 113MB < 256MB L3). scale/shift stay L1/L2-hot.
__global__ __launch_bounds__(256, 4) void ln_apply_kernel(
    const float* __restrict__ x, const float2* __restrict__ stats,
    const float* __restrict__ shift, const float* __restrict__ scale,
    float* __restrict__ out)
{
    const int row = blockIdx.x;               // grid = SEQ
    const int t = threadIdx.x;
    const float2 ms = stats[row];              // uniform -> scalar load
    const float mean = ms.x, rstd = ms.y;
    const float4* x4 = (const float4*)(x + (size_t)row * DIM);
    float4* o4 = (float4*)(out + (size_t)row * DIM);
    const float4* sc4 = (const float4*)scale;
    const float4* sh4 = (const float4*)shift;

    #pragma unroll
    for (int k = 0; k < 3; ++k) {
        int i = t + k * 256;                   // float4 index < 768
        float4 v = x4[i];
        float4 sc = sc4[i];
        float4 sh = sh4[i];
        float4 r;
        r.x = (v.x - mean) * rstd * sc.x + sh.x;
        r.y = (v.y - mean) * rstd * sc.y + sh.y;
        r.z = (v.z - mean) * rstd * sc.z + sh.z;
        r.w = (v.w - mean) * rstd * sc.w + sh.w;
        o4[i] = r;
    }
}

extern "C" void kernel_launch(void* const* d_in, const int* in_sizes, int n_in,
                              void* d_out, int out_size, void* d_ws, size_t ws_size,
                              hipStream_t stream) {
    const float* x   = (const float*)d_in[0];  // [1, 8192, 3072]
    const float* emb = (const float*)d_in[1];  // [1, 3072]
    const float* W   = (const float*)d_in[2];  // [9216, 3072]
    const float* b   = (const float*)d_in[3];  // [9216]
    float* out   = (float*)d_out;                      // [1,8192,3072] flat
    float* gate  = out + (size_t)SEQ * DIM;            // [1,3072] appended
    float* shift = (float*)d_ws;                       // [3072]
    float* scale = shift + DIM;                        // [3072]
    float2* stats = (float2*)(scale + DIM);            // [8192] {mean,rstd}

    gemv3_kernel<<<NROWS / 4, 256, 0, stream>>>(emb, W, b, shift, scale, gate);
    ln_stats_kernel<<<SEQ / 4, 256, 0, stream>>>(x, stats);
    ln_apply_kernel<<<SEQ, 256, 0, stream>>>(x, stats, shift, scale, out);
}